// Round 8
// baseline (137.272 us; speedup 1.0000x reference)
//
#include <hip/hip_runtime.h>
#include <hip/hip_bf16.h>

// Problem constants: B=16, D=256, T_enc=512, T_dec=2048
#define NB 16
#define ND 256
#define NK 512    // T_enc (contraction dim)
#define NT 2048   // T_dec (output cols)

// R1's reg-prefetch + bf16 double-buffer LDS pipeline, FIXED.
// R1 diagnosis: VGPR_Count=64 proves the scheduler SANK the prefetch loads
// below the MFMA block (32 staged floats + 32 frag regs can't fit in 64),
// destroying the overlap -> 56us. Fix: sched_barrier(0) pins the loads above
// compute. R7 proved overlap works (DMA dbuf) but fp32-in-LDS made compute
// fat (+8us); here LDS stays bf16 so compute is the lean R0 form.
// Keeps R6's verified swapped-MFMA f32x4 epilogue + bijective XCD swizzle.
#define BM 128
#define BN 128
#define BK 32
#define NSTEP (NK / BK)   // 16
#define RSA 40   // A LDS row stride in bf16 (80B: 16B-aligned for b128, 2-way banks)
#define RSB 36   // B^T LDS row stride in bf16 (72B = 18 dwords: <=2-way banks on b64)

typedef __attribute__((ext_vector_type(8))) short short8;   // 8 bf16 = 4 VGPRs
typedef __attribute__((ext_vector_type(4))) float f32x4;    // MFMA accumulator

union S8U { short8 v; uint2 u[2]; };
union BF2U { __hip_bfloat162 h; unsigned int u; };

__device__ inline unsigned int pack2bf(float a, float b) {
    BF2U c; c.h = __float22bfloat162_rn(make_float2(a, b));
    return c.u;
}

__global__ __launch_bounds__(256, 2)
void bmm_bf16_mfma(const float* __restrict__ x, const float* __restrict__ path,
                   float* __restrict__ out) {
    // ---- Chunked XCD swizzle (bijective: 512 % 8 == 0). Tile-id = m + 2*n + 32*b,
    // m fastest: the 2 m-blocks sharing a path panel are adjacent in one XCD chunk.
    const int id  = blockIdx.x;                 // 0..511
    const int swz = (id & 7) * 64 + (id >> 3);
    const int b   = swz >> 5;                   // batch 0..15
    const int rem = swz & 31;
    const int n0  = (rem >> 1) * BN;            // 16 n-blocks
    const int m0  = (rem & 1)  * BM;            // 2 m-blocks

    const int t    = threadIdx.x;
    const int lane = t & 63;
    const int wv   = t >> 6;          // wave id 0..3
    const int wr   = (wv >> 1) * 64;  // wave row offset in tile
    const int wc   = (wv & 1) * 64;   // wave col offset in tile
    const int q    = lane >> 4;       // quad 0..3
    const int lm   = lane & 15;

    __shared__ unsigned short As[2][BM * RSA]; // [m][k], k-contiguous, dbuf
    __shared__ unsigned short Bs[2][BN * RSB]; // [n][k] transposed, dbuf

    const float* xg = x    + ((size_t)b * ND + m0) * NK;   // A tile base
    const float* pg = path + (size_t)b * NK * NT + n0;     // B tile base

    const int rowA = t >> 3;   // A staging: row, +32 per chunk
    const int c4   = t & 7;

    f32x4 acc[4][4];
#pragma unroll
    for (int i = 0; i < 4; ++i)
#pragma unroll
        for (int j = 0; j < 4; ++j)
            acc[i][j] = (f32x4){0.f, 0.f, 0.f, 0.f};

    // Prefetch registers (1 K-step in flight): A 16 VGPR, B 16 VGPR.
    float4 pa[4];
    float  pb[4][4];

    auto load_tile = [&](int k0) {
#pragma unroll
        for (int i = 0; i < 4; ++i)
            pa[i] = *reinterpret_cast<const float4*>(
                xg + (size_t)(rowA + i * 32) * NK + k0 + c4 * 4);
#pragma unroll
        for (int i = 0; i < 4; ++i) {
            const int p   = wv * 4 + i;      // 0..15
            const int kr4 = p >> 1;
            const int n   = (p & 1) * 64 + lane;
            const float* src = pg + (size_t)(k0 + kr4 * 4) * NT + n;
            pb[i][0] = src[0 * NT];
            pb[i][1] = src[1 * NT];
            pb[i][2] = src[2 * NT];
            pb[i][3] = src[3 * NT];
        }
    };

    auto write_tile = [&](int bsel) {
#pragma unroll
        for (int i = 0; i < 4; ++i) {
            uint2 w;
            w.x = pack2bf(pa[i].x, pa[i].y);
            w.y = pack2bf(pa[i].z, pa[i].w);
            *reinterpret_cast<uint2*>(&As[bsel][(rowA + i * 32) * RSA + c4 * 4]) = w;
        }
#pragma unroll
        for (int i = 0; i < 4; ++i) {
            const int p   = wv * 4 + i;
            const int kr4 = p >> 1;
            const int n   = (p & 1) * 64 + lane;
            uint2 w;
            w.x = pack2bf(pb[i][0], pb[i][1]);
            w.y = pack2bf(pb[i][2], pb[i][3]);
            *reinterpret_cast<uint2*>(&Bs[bsel][n * RSB + kr4 * 4]) = w;
        }
    };

    auto compute = [&](int bsel) {
        short8 af[4];
        short8 bfrg[4];
#pragma unroll
        for (int mt = 0; mt < 4; ++mt)
            af[mt] = *reinterpret_cast<const short8*>(
                &As[bsel][(wr + mt * 16 + lm) * RSA + q * 8]); // 16B aligned
#pragma unroll
        for (int nt = 0; nt < 4; ++nt) {
            S8U s;
            s.u[0] = *reinterpret_cast<const uint2*>(
                &Bs[bsel][(wc + nt * 16 + lm) * RSB + q * 8]);
            s.u[1] = *reinterpret_cast<const uint2*>(
                &Bs[bsel][(wc + nt * 16 + lm) * RSB + q * 8 + 4]);
            bfrg[nt] = s.v;
        }
        // Swapped operands (harness-verified R1-R3,R6,R7): lane (q,lm) holds
        // C[m = lm][n = q*4 + r] -> f32x4 epilogue stores.
#pragma unroll
        for (int mt = 0; mt < 4; ++mt)
#pragma unroll
            for (int nt = 0; nt < 4; ++nt)
                acc[mt][nt] = __builtin_amdgcn_mfma_f32_16x16x32_bf16(
                    bfrg[nt], af[mt], acc[mt][nt], 0, 0, 0);
    };

    // ---- Pipeline: prologue stages step 0; each iter issues loads for s+1,
    // THEN (fence) computes s, then drains+writes s+1 into the other buffer.
    // The sched_barrier(0) is the R1 fix: without it the scheduler sinks the
    // loads below the MFMAs to cut register pressure (R1: VGPR_Count=64),
    // which serializes the HBM latency instead of hiding it under compute.
    load_tile(0);
    write_tile(0);
    __syncthreads();

    int cur = 0;
    for (int s = 0; s < NSTEP - 1; ++s) {
        load_tile((s + 1) * BK);               // issue 20 VMEM -> in flight
        __builtin_amdgcn_sched_barrier(0);     // pin loads ABOVE compute
        compute(cur);                          // ds_read + 16 MFMA overlap HBM
        write_tile(cur ^ 1);                   // vmcnt drain lands here
        __syncthreads();                       // single barrier per K-step
        cur ^= 1;
    }
    compute(cur);                              // last step

    // ---- Epilogue: lane (q,lm) holds rows m=lm, cols q*4+0..3 (verified)
    float* og = out + ((size_t)b * ND + m0 + wr) * NT + n0 + wc;
#pragma unroll
    for (int mt = 0; mt < 4; ++mt)
#pragma unroll
        for (int nt = 0; nt < 4; ++nt)
            *reinterpret_cast<f32x4*>(
                &og[(size_t)(mt * 16 + lm) * NT + nt * 16 + q * 4]) = acc[mt][nt];
}

extern "C" void kernel_launch(void* const* d_in, const int* in_sizes, int n_in,
                              void* d_out, int out_size, void* d_ws, size_t ws_size,
                              hipStream_t stream) {
    const float* x    = (const float*)d_in[0];   // [16, 256, 512]
    const float* path = (const float*)d_in[1];   // [16, 512, 2048]
    float* out        = (float*)d_out;           // [16, 256, 2048]
    dim3 grid(512);                              // 2 m * 16 n * 16 b, 1D for swizzle
    dim3 block(256);
    bmm_bf16_mfma<<<grid, block, 0, stream>>>(x, path, out);
}

// Round 9
// 124.765 us; speedup vs baseline: 1.1002x; 1.1002x over previous
//
#include <hip/hip_runtime.h>
#include <hip/hip_bf16.h>

// Problem constants: B=16, D=256, T_enc=512, T_dec=2048
#define NB 16
#define ND 256
#define NK 512    // T_enc (contraction dim)
#define NT 2048   // T_dec (output cols)

// R7 (DMA + fp32 dbuf LDS, harness-verified) with ONE change: the T4
// counted-vmcnt schedule. R7 drained vmcnt(0) at every __syncthreads -> the
// next tile's DMAs could not span the barrier (m218: drain-0 forfeits the
// entire pipeline, counted-vmcnt is +38-73%). Here: raw s_barrier + inline
// `s_waitcnt vmcnt(8)` -> 8 DMAs (next tile) stay in flight across barriers.
// Per iter: vmcnt(8); barrier; compute(cur); barrier; stage(cur, s+2).
// Buffer-overwrite hazard: stage(buf X, s+2) is after barrier2 of iter s,
// reads of buf X (step s) are before it. Cross-wave DMA visibility: each
// wave passes its own vmcnt(8) BEFORE barrier1 (m201 pattern).
#define BM 128
#define BN 128
#define BK 32
#define NSTEP (NK / BK)   // 16

typedef __attribute__((ext_vector_type(8))) short short8;   // 8 bf16 = 4 VGPRs
typedef __attribute__((ext_vector_type(4))) float f32x4;    // MFMA accumulator

union BF2U { __hip_bfloat162 h; unsigned int u; };
union S8U4 { short8 v; unsigned int u[4]; };

__device__ inline unsigned int pack2bf(float a, float b) {
    BF2U c; c.h = __float22bfloat162_rn(make_float2(a, b));
    return c.u;
}

// 16B-per-lane async global->LDS DMA. LDS dest = wave-uniform base + lane*16.
#define GLOAD_LDS(g, l) __builtin_amdgcn_global_load_lds(                     \
    (const __attribute__((address_space(1))) void*)(g),                       \
    (__attribute__((address_space(3))) void*)(l), 16, 0, 0)

#define VMCNT8() asm volatile("s_waitcnt vmcnt(8)" ::: "memory")
#define VMCNT0() asm volatile("s_waitcnt vmcnt(0)" ::: "memory")
#define BAR()    __builtin_amdgcn_s_barrier()
#define SCHED0() __builtin_amdgcn_sched_barrier(0)

__global__ __launch_bounds__(256, 2)
void bmm_bf16_mfma(const float* __restrict__ x, const float* __restrict__ path,
                   float* __restrict__ out) {
    const int n0 = blockIdx.x * BN;
    const int m0 = blockIdx.y * BM;
    const int b  = blockIdx.z;
    const int t    = threadIdx.x;
    const int lane = t & 63;
    const int wv   = t >> 6;          // wave id 0..3
    const int wr   = (wv >> 1) * 64;  // wave row offset in tile
    const int wc   = (wv & 1) * 64;   // wave col offset in tile
    const int q    = lane >> 4;       // quad 0..3
    const int lm   = lane & 15;

    // 64 KB: buf p at float offset p*8192. A tile (128x32 f32, 128B rows) at +0,
    // B tile (32x128 f32, 512B rows) at +4096. Linear layouts, data pre-swizzled
    // at the SOURCE so swizzled reads are conflict-free (R7-verified):
    //   A: 16B slot s of row r holds k-slot (s ^ (r&7))
    //   B: 16B slot s of k-row k holds col-slot (s ^ (((k>>3)&1)<<2))
    __shared__ float smem[2 * 8192];

    const float* xg = x    + ((size_t)b * ND + m0) * NK;   // A tile base
    const float* pg = path + (size_t)b * NK * NT + n0;     // B tile base

    // ---- Stage pointers: per-lane global src (pre-swizzled), wave-uniform LDS
    // chunk base. Advance global ptrs by BK each stage call (calls are in
    // k-order: steps 0,1,2,...,15).
    const float* gA[4]; const float* gB[4];
    float* lA[4];       float* lB[4];
#pragma unroll
    for (int i = 0; i < 4; ++i) {
        const int c  = wv * 4 + i;             // chunk 0..15, 1 KiB each
        const int ra = c * 8 + (lane >> 3);
        const int sa = (lane & 7) ^ (ra & 7);  // pre-swizzled source k-slot
        gA[i] = xg + (size_t)ra * NK + sa * 4;
        lA[i] = &smem[c * 256];
        const int kb = c * 2 + (lane >> 5);
        const int sb = (lane & 31) ^ (((kb >> 3) & 1) << 2);
        gB[i] = pg + (size_t)kb * NT + sb * 4;
        lB[i] = &smem[4096 + c * 256];
    }

    auto stage = [&](int bo) {                 // bo = buffer float offset (0/8192)
#pragma unroll
        for (int i = 0; i < 4; ++i) { GLOAD_LDS(gA[i], lA[i] + bo); gA[i] += BK; }
#pragma unroll
        for (int i = 0; i < 4; ++i) { GLOAD_LDS(gB[i], lB[i] + bo); gB[i] += (size_t)BK * NT; }
    };

    // ---- Compute-phase read offsets (R7-verified).
    const int vA0 = (wr + lm) * 32 + (((2 * q + 0) ^ (lm & 7)) * 4);
    const int vA1 = (wr + lm) * 32 + (((2 * q + 1) ^ (lm & 7)) * 4);
    int colB[4];
#pragma unroll
    for (int nt = 0; nt < 4; ++nt)
        colB[nt] = wc + ((nt ^ (q & 1)) * 16) + lm;

    f32x4 acc[4][4];
#pragma unroll
    for (int i = 0; i < 4; ++i)
#pragma unroll
        for (int j = 0; j < 4; ++j)
            acc[i][j] = (f32x4){0.f, 0.f, 0.f, 0.f};

    auto compute = [&](int bo) {
        short8 afr[4], bfr[4];
#pragma unroll
        for (int mt = 0; mt < 4; ++mt) {
            float4 x0 = *reinterpret_cast<const float4*>(&smem[bo + mt * 512 + vA0]);
            float4 x1 = *reinterpret_cast<const float4*>(&smem[bo + mt * 512 + vA1]);
            S8U4 s;
            s.u[0] = pack2bf(x0.x, x0.y);
            s.u[1] = pack2bf(x0.z, x0.w);
            s.u[2] = pack2bf(x1.x, x1.y);
            s.u[3] = pack2bf(x1.z, x1.w);
            afr[mt] = s.v;
        }
#pragma unroll
        for (int nt = 0; nt < 4; ++nt) {
            const float* bp = &smem[bo + 4096 + q * 1024 + colB[nt]];
            float f0 = bp[0 * 128], f1 = bp[1 * 128], f2 = bp[2 * 128], f3 = bp[3 * 128];
            float f4 = bp[4 * 128], f5 = bp[5 * 128], f6 = bp[6 * 128], f7 = bp[7 * 128];
            S8U4 s;
            s.u[0] = pack2bf(f0, f1);
            s.u[1] = pack2bf(f2, f3);
            s.u[2] = pack2bf(f4, f5);
            s.u[3] = pack2bf(f6, f7);
            bfr[nt] = s.v;
        }
        // Swapped operands (harness-verified R1-R3,R6,R7): lane (q,lm) holds
        // C[m = lm][n = q*4 + r] -> f32x4 epilogue stores.
#pragma unroll
        for (int mt = 0; mt < 4; ++mt)
#pragma unroll
            for (int nt = 0; nt < 4; ++nt)
                acc[mt][nt] = __builtin_amdgcn_mfma_f32_16x16x32_bf16(
                    bfr[nt], afr[mt], acc[mt][nt], 0, 0, 0);
    };

    // ---- T4 counted-vmcnt pipeline. Steady state: 16 DMAs outstanding
    // (8 = step s into buf[s&1], 8 = step s+1). vmcnt(8) releases only the
    // older 8; the newer 8 stay in flight ACROSS both barriers.
    stage(0);        // step 0 -> buf0   (8 DMA)
    stage(8192);     // step 1 -> buf1   (8 DMA; 16 outstanding)

    for (int s = 0; s < NSTEP - 2; ++s) {      // s = 0..13
        VMCNT8();                              // step s landed (step s+1 in flight)
        BAR();                                 // all waves' DMAs for step s visible
        SCHED0();
        compute((s & 1) * 8192);               // read buf[s&1]
        BAR();                                 // everyone done reading buf[s&1]
        SCHED0();
        stage((s & 1) * 8192);                 // step s+2 -> buf[s&1]; 16 in flight
    }
    // s = 14: outstanding 16 (steps 14,15)
    VMCNT8();  BAR();  SCHED0();
    compute(0);                                // step 14 <- buf0
    // s = 15: outstanding 8 (step 15)
    VMCNT0();  BAR();  SCHED0();
    compute(8192);                             // step 15 <- buf1

    // ---- Epilogue: lane (q,lm) holds rows m=lm, cols q*4+0..3 (verified)
    float* og = out + ((size_t)b * ND + m0 + wr) * NT + n0 + wc;
#pragma unroll
    for (int mt = 0; mt < 4; ++mt)
#pragma unroll
        for (int nt = 0; nt < 4; ++nt)
            *reinterpret_cast<f32x4*>(
                &og[(size_t)(mt * 16 + lm) * NT + nt * 16 + q * 4]) = acc[mt][nt];
}

extern "C" void kernel_launch(void* const* d_in, const int* in_sizes, int n_in,
                              void* d_out, int out_size, void* d_ws, size_t ws_size,
                              hipStream_t stream) {
    const float* x    = (const float*)d_in[0];   // [16, 256, 512]
    const float* path = (const float*)d_in[1];   // [16, 512, 2048]
    float* out        = (float*)d_out;           // [16, 256, 2048]
    dim3 grid(NT / BN, ND / BM, NB);             // (16, 2, 16) = 512 blocks
    dim3 block(256);
    bmm_bf16_mfma<<<grid, block, 0, stream>>>(x, path, out);
}